// Round 9
// baseline (447.133 us; speedup 1.0000x reference)
//
#include <hip/hip_runtime.h>

#define DEV static __device__ __forceinline__

// ---- DPP helpers (row = 16 lanes). Proven in R1/R4/R6/R8. ----
template<int CTRL>
DEV float dppf(float x){
  int v = __builtin_amdgcn_update_dpp(0, __builtin_bit_cast(int, x), CTRL, 0xF, 0xF, true);
  return __builtin_bit_cast(float, v);
}
// sum over each 16-lane row; every lane of the row gets the full row sum
DEV float rowsum16(float v){
  v += dppf<0xB1>(v);    // quad_perm(1,0,3,2): xor 1
  v += dppf<0x4E>(v);    // quad_perm(2,3,0,1): xor 2
  v += dppf<0x124>(v);   // row_ror:4
  v += dppf<0x128>(v);   // row_ror:8
  return v;
}
// cross-row (only used in the throughput-parallel Yx kernel, never in the scan)
DEV float sx16(float v){ return __shfl_xor(v, 16); }
DEV float sx32(float v){ return __shfl_xor(v, 32); }
DEV float full64(float v){
  float r = rowsum16(v);
  r += sx16(r); r += sx32(r);
  return r;
}

DEV float fexp(float x){ return __builtin_amdgcn_exp2f(x * 1.44269504088896341f); }
DEV float frcp(float x){ return __builtin_amdgcn_rcpf(x); }
DEV float frsq(float x){ return __builtin_amdgcn_rsqf(x); }
DEV float fsqrt_(float x){ return __builtin_amdgcn_sqrtf(x); }
DEV float sigmoidf_(float x){ return frcp(1.f + fexp(-x)); }
DEV float tanhfast(float x){ return 1.f - 2.f*frcp(1.f + fexp(2.f*x)); }

// =================== Kernel 1: Yx precompute (throughput-bound) ===================
// Yx[row][q] = sum_col ew[q,col]*exp(fw[col])*x[row,col] + eb[q],  row = e*T+t
__global__ void yx_pre(const float* __restrict__ x, const float* __restrict__ fw,
                       const float* __restrict__ ew, const float* __restrict__ eb,
                       float* __restrict__ yx, long long nrows)
{
  const int lane = threadIdx.x & 63;
  const long long wid = (long long)blockIdx.x * (blockDim.x >> 6) + (threadIdx.x >> 6);
  const long long nw  = (long long)gridDim.x * (blockDim.x >> 6);
  float w0_,w1_,w2_,w3_,v0_,v1_,v2_,v3_;
  {
    const float f0 = fexp(fw[2*lane]), f1 = fexp(fw[2*lane+1]);
    w0_ = ew[0*192+2*lane]*f0; v0_ = ew[0*192+2*lane+1]*f1;
    w1_ = ew[1*192+2*lane]*f0; v1_ = ew[1*192+2*lane+1]*f1;
    w2_ = ew[2*192+2*lane]*f0; v2_ = ew[2*192+2*lane+1]*f1;
    w3_ = ew[3*192+2*lane]*f0; v3_ = ew[3*192+2*lane+1]*f1;
  }
  const float b0=eb[0], b1=eb[1], b2=eb[2], b3=eb[3];
  for (long long row = wid; row < nrows; row += nw){
    const float2 xv = *(const float2*)(x + row*128 + 2*lane);
    float a0 = fmaf(v0_,xv.y, w0_*xv.x);
    float a1 = fmaf(v1_,xv.y, w1_*xv.x);
    float a2 = fmaf(v2_,xv.y, w2_*xv.x);
    float a3 = fmaf(v3_,xv.y, w3_*xv.x);
    a0 = full64(a0); a1 = full64(a1); a2 = full64(a2); a3 = full64(a3);
    if (lane == 0){
      float4 o; o.x=a0+b0; o.y=a1+b1; o.z=a2+b2; o.w=a3+b3;
      *(float4*)(yx + row*4) = o;
    }
  }
}

// =================== Kernel 2: recurrence, 16 lanes per element ===================
// wave = 4 rows x 16 lanes; row owns one batch element; ALL reductions rowsum16.
// lane (row r, pos l): owns amplitude k=l (F-matvec) and hidden units 4l..4l+3.
// 4x unrolled: each step's store data in its own scope -> no store-ack stall.
__global__ void __launch_bounds__(64) qssm16(
  const float* __restrict__ ew, const float* __restrict__ exw,
  const float* __restrict__ exb,const float* __restrict__ vw,
  const float* __restrict__ nrw,const float* __restrict__ nrb,
  const float* __restrict__ yx, float* __restrict__ out,
  int T, int Bn, long long hToff)
{
  const int lane = threadIdx.x;
  const int l    = lane & 15;
  const int rrow = lane >> 4;
  int e = blockIdx.x*4 + rrow; if (e >= Bn) e = Bn-1;

  // ---------- build fixed circuit matrix M (16x16 complex) once ----------
  __shared__ float MrS[16][16];
  __shared__ float MiS[16][16];
  if (lane < 16){
    const int j = lane;
    float w2[2][3][4];
    #pragma unroll
    for (int ll=0;ll<2;ll++)
      #pragma unroll
      for (int g=0;g<3;g++)
        #pragma unroll
        for (int i=0;i<4;i++) w2[ll][g][i] = 0.5f * vw[(ll*3+g)*4+i];
    float sr[16], si[16];
    #pragma unroll
    for (int n=0;n<16;n++){ sr[n] = (n==j)?1.f:0.f; si[n]=0.f; }
    #pragma unroll
    for (int ll=0;ll<2;ll++){
      #pragma unroll
      for (int cq=0;cq<4;cq++){
        const int tq=(cq+1)&3, mc=1<<(3-cq), mt=1<<(3-tq);
        #pragma unroll
        for (int n=0;n<16;n++){
          if ((n&mc) && !(n&mt)){
            const int n1 = n|mt;
            float tr=sr[n], ti=si[n];
            sr[n]=sr[n1]; si[n]=si[n1];
            sr[n1]=tr;    si[n1]=ti;
          }
        }
      }
      #pragma unroll
      for (int i=0;i<4;i++){
        const int m=1<<(3-i);
        const float cx=cosf(w2[ll][0][i]), sxx=sinf(w2[ll][0][i]);
        const float cy=cosf(w2[ll][1][i]), sy=sinf(w2[ll][1][i]);
        const float cz=cosf(w2[ll][2][i]), sz=sinf(w2[ll][2][i]);
        #pragma unroll
        for (int n=0;n<16;n++){
          if (!(n&m)){
            const int n1=n|m;
            float a0r=sr[n], a0i=si[n], a1r=sr[n1], a1i=si[n1];
            float b0r = cx*a0r + sxx*a1i, b0i = cx*a0i - sxx*a1r;
            float b1r = sxx*a0i + cx*a1r, b1i = -sxx*a0r + cx*a1i;
            float c0r = cy*b0r - sy*b1r, c0i = cy*b0i - sy*b1i;
            float c1r = sy*b0r + cy*b1r, c1i = sy*b0i + cy*b1i;
            sr[n]  = cz*c0r + sz*c0i;  si[n]  = cz*c0i - sz*c0r;
            sr[n1] = cz*c1r - sz*c1i;  si[n1] = cz*c1i + sz*c1r;
          }
        }
      }
    }
    #pragma unroll
    for (int n=0;n<16;n++){ MrS[n][j]=sr[n]; MiS[n][j]=si[n]; }
  }
  __syncthreads();

  // M row for this lane's amplitude k=l
  float Mr[16], Mi[16];
  #pragma unroll
  for (int j=0;j<16;j++){ Mr[j]=MrS[l][j]; Mi[j]=MiS[l][j]; }

  // ---------- per-lane weights: 4 hidden units u=4l..4l+3 ----------
  float Wg[4][4], Wi_[4][4], Wd[4][4], bg[4], bi[4], bd[4], lw4[4], lb4[4], WL[4][4];
  #pragma unroll
  for (int v=0;v<4;v++){
    const int u = 4*l+v;
    #pragma unroll
    for (int m=0;m<4;m++){
      Wg[v][m] = exw[(u      )*4+m];
      Wi_[v][m]= exw[(64 + u )*4+m];
      Wd[v][m] = exw[(128 + u)*4+m];
    }
    bg[v]=exb[u]; bi[v]=exb[64+u]; bd[v]=exb[128+u];
    lw4[v]=nrw[u]; lb4[v]=nrb[u];
  }
  float C1[4], C2[4];
  #pragma unroll
  for (int q=0;q<4;q++){
    float c1p=0.f, c2p=0.f;
    #pragma unroll
    for (int v=0;v<4;v++){
      const float whq = ew[q*192 + 128 + 4*l + v];
      WL[q][v] = whq * lw4[v];
      c1p += WL[q][v];
      c2p = fmaf(whq, lb4[v], c2p);
    }
    C1[q] = rowsum16(c1p);
    C2[q] = rowsum16(c2p);
  }

  // Z-expectation signs for amplitude k=l (qubit q <-> bit 3-q)
  const float sg0 = (l & 8) ? -1.f : 1.f;
  const float sg1 = (l & 4) ? -1.f : 1.f;
  const float sg2 = (l & 2) ? -1.f : 1.f;
  const float sg3 = (l & 1) ? -1.f : 1.f;

  const float* yxp = yx + (size_t)e * T * 4;
  float* op = out + (size_t)e * T * 64 + 4*l;

  // recurrent state
  float Sq[4] = {0.f,0.f,0.f,0.f};
  float cstv[4] = {0.f,0.f,0.f,0.f};
  float mu=0.f, rstd=0.f, w0g=0.f;
  float4 hlast = {0.f,0.f,0.f,0.f};

  // 4-deep prefetch buffers (consumed 4 steps after load)
  float4 yA = *(const float4*)(yxp + 0);
  float4 yB = *(const float4*)(yxp + 4);
  float4 yC = *(const float4*)(yxp + 8);
  float4 yD = *(const float4*)(yxp + 12);

#define STEP(TCUR, YBUF, SAVELAST)                                                \
  {                                                                               \
    const int t_ = (TCUR);                                                        \
    const float y0 = YBUF.x + fmaf(w0g, C2[0], rstd*fmaf(-mu, C1[0], Sq[0]));     \
    const float y1 = YBUF.y + fmaf(w0g, C2[1], rstd*fmaf(-mu, C1[1], Sq[1]));     \
    const float y2 = YBUF.z + fmaf(w0g, C2[2], rstd*fmaf(-mu, C1[2], Sq[2]));     \
    const float y3 = YBUF.w + fmaf(w0g, C2[3], rstd*fmaf(-mu, C1[3], Sq[3]));     \
    { const int tn = (t_+4 < T) ? (t_+4) : (T-1);                                 \
      YBUF = *(const float4*)(yxp + (size_t)tn*4); }                              \
    /* encoded qubit vectors (phase-rotated: |0> comp real) */                    \
    float qa[4]; float qbr[4], qbi[4];                                            \
    {                                                                             \
      auto mkv = [&](float u, float& a, float& br, float& bim){                   \
        const float r2 = u*u;                                                     \
        const float c1 = frsq(fmaf(u,u,1.f));                                     \
        const float tt = (0.5f*u)*c1;                                             \
        a = fsqrt_(0.5f - tt);                                                    \
        const float bb = fsqrt_(0.5f + tt);                                       \
        const float cp = frsq(fmaf(r2,r2,1.f));                                   \
        const float sp = r2*cp;                                                   \
        br = bb*cp; bim = bb*sp;                                                  \
      };                                                                          \
      mkv(y0,qa[0],qbr[0],qbi[0]); mkv(y1,qa[1],qbr[1],qbi[1]);                   \
      mkv(y2,qa[2],qbr[2],qbi[2]); mkv(y3,qa[3],qbr[3],qbi[3]);                   \
    }                                                                             \
    /* tensor halves A = v0 (x) v1, B = v2 (x) v3 */                              \
    float Ar[4], Ai[4], Br_[4], Bi_[4];                                           \
    Ar[0]=qa[0]*qa[1];                    Ai[0]=0.f;                              \
    Ar[1]=qa[0]*qbr[1];                   Ai[1]=qa[0]*qbi[1];                     \
    Ar[2]=qbr[0]*qa[1];                   Ai[2]=qbi[0]*qa[1];                     \
    Ar[3]=fmaf(-qbi[0],qbi[1],qbr[0]*qbr[1]); Ai[3]=fmaf(qbi[0],qbr[1],qbr[0]*qbi[1]); \
    Br_[0]=qa[2]*qa[3];                   Bi_[0]=0.f;                             \
    Br_[1]=qa[2]*qbr[3];                  Bi_[1]=qa[2]*qbi[3];                    \
    Br_[2]=qbr[2]*qa[3];                  Bi_[2]=qbi[2]*qa[3];                    \
    Br_[3]=fmaf(-qbi[2],qbi[3],qbr[2]*qbr[3]); Bi_[3]=fmaf(qbi[2],qbr[3],qbr[2]*qbi[3]); \
    /* F_k = sum_m A_m * (sum_n M[k][4m+n] * B_n)  (all in-lane) */               \
    float Fr=0.f, Fi=0.f;                                                         \
    _Pragma("unroll")                                                             \
    for (int m=0;m<4;m++){                                                        \
      float Gr=0.f, Gi=0.f;                                                       \
      _Pragma("unroll")                                                           \
      for (int n=0;n<4;n++){                                                      \
        const float mr=Mr[4*m+n], mi=Mi[4*m+n];                                   \
        Gr = fmaf(mr,Br_[n],Gr); Gr = fmaf(-mi,Bi_[n],Gr);                        \
        Gi = fmaf(mr,Bi_[n],Gi); Gi = fmaf( mi,Br_[n],Gi);                        \
      }                                                                           \
      Fr = fmaf(Ar[m],Gr,Fr); Fr = fmaf(-Ai[m],Gi,Fr);                            \
      Fi = fmaf(Ar[m],Gi,Fi); Fi = fmaf( Ai[m],Gr,Fi);                            \
    }                                                                             \
    const float p = fmaf(Fr,Fr, Fi*Fi);                                           \
    /* Z expectations: one signed rowsum16 per qubit (row-local!) */              \
    const float q0 = rowsum16(sg0*p);                                             \
    const float q1 = rowsum16(sg1*p);                                             \
    const float q2 = rowsum16(sg2*p);                                             \
    const float q3 = rowsum16(sg3*p);                                             \
    const float z0=y0+q0, z1=y1+q1, z2=y2+q2, z3=y3+q3;                           \
    /* exit matvec + gates for this lane's 4 hidden units */                      \
    float prearr[4];                                                              \
    _Pragma("unroll")                                                             \
    for (int v=0;v<4;v++){                                                        \
      const float og = fmaf(Wg[v][3],z3, fmaf(Wg[v][2],z2, fmaf(Wg[v][1],z1, fmaf(Wg[v][0],z0, bg[v])))); \
      const float oi = fmaf(Wi_[v][3],z3, fmaf(Wi_[v][2],z2, fmaf(Wi_[v][1],z1, fmaf(Wi_[v][0],z0, bi[v])))); \
      const float od = fmaf(Wd[v][3],z3, fmaf(Wd[v][2],z2, fmaf(Wd[v][1],z1, fmaf(Wd[v][0],z0, bd[v])))); \
      float g = sigmoidf_(og);                                                    \
      g = fminf(fmaxf(g, 0.05f), 0.95f);                                          \
      const float ig = sigmoidf_(oi);                                             \
      const float dt = tanhfast(od);                                              \
      cstv[v] = fmaf(fmaf(-0.9f, g, 0.9f), cstv[v], ig*dt);                       \
      prearr[v] = g * tanhfast(cstv[v]);                                          \
    }                                                                             \
    /* LayerNorm + S-fold: 6 independent row-local reductions */                  \
    const float s1p = (prearr[0]+prearr[1])+(prearr[2]+prearr[3]);                \
    const float s2p = fmaf(prearr[3],prearr[3], fmaf(prearr[2],prearr[2],         \
                      fmaf(prearr[1],prearr[1], prearr[0]*prearr[0])));           \
    float t0p=0.f,t1p=0.f,t2p=0.f,t3p=0.f;                                        \
    _Pragma("unroll")                                                             \
    for (int v=0;v<4;v++){                                                        \
      t0p = fmaf(WL[0][v],prearr[v],t0p);                                         \
      t1p = fmaf(WL[1][v],prearr[v],t1p);                                         \
      t2p = fmaf(WL[2][v],prearr[v],t2p);                                         \
      t3p = fmaf(WL[3][v],prearr[v],t3p);                                         \
    }                                                                             \
    const float s1 = rowsum16(s1p);                                               \
    const float s2 = rowsum16(s2p);                                               \
    Sq[0] = rowsum16(t0p); Sq[1] = rowsum16(t1p);                                 \
    Sq[2] = rowsum16(t2p); Sq[3] = rowsum16(t3p);                                 \
    mu = s1 * (1.f/64.f);                                                         \
    const float var = fmaf(s2, 1.f/64.f, -mu*mu);                                 \
    rstd = frsq(var + 1e-5f);                                                     \
    float4 hv;                                                                    \
    hv.x = fmaf((prearr[0]-mu)*rstd, lw4[0], lb4[0]);                             \
    hv.y = fmaf((prearr[1]-mu)*rstd, lw4[1], lb4[1]);                             \
    hv.z = fmaf((prearr[2]-mu)*rstd, lw4[2], lb4[2]);                             \
    hv.w = fmaf((prearr[3]-mu)*rstd, lw4[3], lb4[3]);                             \
    *(float4*)(op + (size_t)t_*64) = hv;                                          \
    if (SAVELAST) hlast = hv;                                                     \
    w0g = 1.f;                                                                    \
  }

  // T assumed a multiple of 4 (T=512); 4 distinct step scopes per iteration ->
  // compiler renames store-data/prefetch regs; store-ack waits land 4 steps later.
  for (int t=0; t<T; t+=4){
    STEP(t,   yA, 0);
    STEP(t+1, yB, 0);
    STEP(t+2, yC, 0);
    STEP(t+3, yD, 1);
  }
#undef STEP

  // final hidden state h_T
  *(float4*)(out + hToff + (size_t)e*64 + 4*l) = hlast;
}

extern "C" void kernel_launch(void* const* d_in, const int* in_sizes, int n_in,
                              void* d_out, int out_size, void* d_ws, size_t ws_size,
                              hipStream_t stream)
{
  const float* x   = (const float*)d_in[0];
  const float* fw  = (const float*)d_in[1];
  const float* ew  = (const float*)d_in[2];
  const float* eb  = (const float*)d_in[3];
  const float* exw = (const float*)d_in[4];
  const float* exb = (const float*)d_in[5];
  const float* vw  = (const float*)d_in[6];
  const float* nw  = (const float*)d_in[7];
  const float* nb  = (const float*)d_in[8];

  const long long BT = in_sizes[0] / 128;           // B*T
  const int B = (int)((long long)out_size/64 - BT); // out = B*T*64 + B*64
  const int T = (int)(BT / B);

  float* yxbuf = (float*)d_ws;                      // B*T*4 floats (2 MB)

  yx_pre<<<1024, 256, 0, stream>>>(x, fw, ew, eb, yxbuf, BT);
  qssm16<<<(B+3)/4, 64, 0, stream>>>(ew, exw, exb, vw, nw, nb,
                                     yxbuf, (float*)d_out, T, B, (long long)BT*64);
}

// Round 11
// 441.572 us; speedup vs baseline: 1.0126x; 1.0126x over previous
//
#include <hip/hip_runtime.h>

#define DEV static __device__ __forceinline__

// ---- DPP helpers (row = 16 lanes). Proven in R1/R4/R6/R8. ----
template<int CTRL>
DEV float dppf(float x){
  int v = __builtin_amdgcn_update_dpp(0, __builtin_bit_cast(int, x), CTRL, 0xF, 0xF, true);
  return __builtin_bit_cast(float, v);
}
// sum over each 16-lane row; every lane of the row gets the full row sum
DEV float rowsum16(float v){
  v += dppf<0xB1>(v);    // quad_perm(1,0,3,2): xor 1
  v += dppf<0x4E>(v);    // quad_perm(2,3,0,1): xor 2
  v += dppf<0x124>(v);   // row_ror:4
  v += dppf<0x128>(v);   // row_ror:8
  return v;
}
// cross-row (only used in the throughput-parallel Yx kernel, never in the scan)
DEV float sx16(float v){ return __shfl_xor(v, 16); }
DEV float sx32(float v){ return __shfl_xor(v, 32); }
DEV float full64(float v){
  float r = rowsum16(v);
  r += sx16(r); r += sx32(r);
  return r;
}

DEV float fexp(float x){ return __builtin_amdgcn_exp2f(x * 1.44269504088896341f); }
DEV float frcp(float x){ return __builtin_amdgcn_rcpf(x); }
DEV float frsq(float x){ return __builtin_amdgcn_rsqf(x); }
DEV float fsqrt_(float x){ return __builtin_amdgcn_sqrtf(x); }
DEV float sigmoidf_(float x){ return frcp(1.f + fexp(-x)); }
DEV float tanhfast(float x){ return 1.f - 2.f*frcp(1.f + fexp(2.f*x)); }

// =================== Kernel 1: Yx precompute (throughput-bound) ===================
__global__ void yx_pre(const float* __restrict__ x, const float* __restrict__ fw,
                       const float* __restrict__ ew, const float* __restrict__ eb,
                       float* __restrict__ yx, long long nrows)
{
  const int lane = threadIdx.x & 63;
  const long long wid = (long long)blockIdx.x * (blockDim.x >> 6) + (threadIdx.x >> 6);
  const long long nw  = (long long)gridDim.x * (blockDim.x >> 6);
  float w0_,w1_,w2_,w3_,v0_,v1_,v2_,v3_;
  {
    const float f0 = fexp(fw[2*lane]), f1 = fexp(fw[2*lane+1]);
    w0_ = ew[0*192+2*lane]*f0; v0_ = ew[0*192+2*lane+1]*f1;
    w1_ = ew[1*192+2*lane]*f0; v1_ = ew[1*192+2*lane+1]*f1;
    w2_ = ew[2*192+2*lane]*f0; v2_ = ew[2*192+2*lane+1]*f1;
    w3_ = ew[3*192+2*lane]*f0; v3_ = ew[3*192+2*lane+1]*f1;
  }
  const float b0=eb[0], b1=eb[1], b2=eb[2], b3=eb[3];
  for (long long row = wid; row < nrows; row += nw){
    const float2 xv = *(const float2*)(x + row*128 + 2*lane);
    float a0 = fmaf(v0_,xv.y, w0_*xv.x);
    float a1 = fmaf(v1_,xv.y, w1_*xv.x);
    float a2 = fmaf(v2_,xv.y, w2_*xv.x);
    float a3 = fmaf(v3_,xv.y, w3_*xv.x);
    a0 = full64(a0); a1 = full64(a1); a2 = full64(a2); a3 = full64(a3);
    if (lane == 0){
      float4 o; o.x=a0+b0; o.y=a1+b1; o.z=a2+b2; o.w=a3+b3;
      *(float4*)(yx + row*4) = o;
    }
  }
}

// =================== Kernel 2: recurrence, 16 lanes per element ===================
// wave = 4 rows x 16 lanes; row owns one batch element; ALL reductions rowsum16.
// VMEM batched: 8 reg-only steps, then refill the JUST-CONSUMED buffer (R10 bug:
// refilled the other buffer before its consumption), then 8 stores.
__global__ void __launch_bounds__(64) qssm16(
  const float* __restrict__ ew, const float* __restrict__ exw,
  const float* __restrict__ exb,const float* __restrict__ vw,
  const float* __restrict__ nrw,const float* __restrict__ nrb,
  const float* __restrict__ yx, float* __restrict__ out,
  int T, int Bn, long long hToff)
{
  const int lane = threadIdx.x;
  const int l    = lane & 15;
  const int rrow = lane >> 4;
  int e = blockIdx.x*4 + rrow; if (e >= Bn) e = Bn-1;

  // ---------- build fixed circuit matrix M (16x16 complex) once ----------
  __shared__ float MrS[16][16];
  __shared__ float MiS[16][16];
  if (lane < 16){
    const int j = lane;
    float w2[2][3][4];
    #pragma unroll
    for (int ll=0;ll<2;ll++)
      #pragma unroll
      for (int g=0;g<3;g++)
        #pragma unroll
        for (int i=0;i<4;i++) w2[ll][g][i] = 0.5f * vw[(ll*3+g)*4+i];
    float sr[16], si[16];
    #pragma unroll
    for (int n=0;n<16;n++){ sr[n] = (n==j)?1.f:0.f; si[n]=0.f; }
    #pragma unroll
    for (int ll=0;ll<2;ll++){
      #pragma unroll
      for (int cq=0;cq<4;cq++){
        const int tq=(cq+1)&3, mc=1<<(3-cq), mt=1<<(3-tq);
        #pragma unroll
        for (int n=0;n<16;n++){
          if ((n&mc) && !(n&mt)){
            const int n1 = n|mt;
            float tr=sr[n], ti=si[n];
            sr[n]=sr[n1]; si[n]=si[n1];
            sr[n1]=tr;    si[n1]=ti;
          }
        }
      }
      #pragma unroll
      for (int i=0;i<4;i++){
        const int m=1<<(3-i);
        const float cx=cosf(w2[ll][0][i]), sxx=sinf(w2[ll][0][i]);
        const float cy=cosf(w2[ll][1][i]), sy=sinf(w2[ll][1][i]);
        const float cz=cosf(w2[ll][2][i]), sz=sinf(w2[ll][2][i]);
        #pragma unroll
        for (int n=0;n<16;n++){
          if (!(n&m)){
            const int n1=n|m;
            float a0r=sr[n], a0i=si[n], a1r=sr[n1], a1i=si[n1];
            float b0r = cx*a0r + sxx*a1i, b0i = cx*a0i - sxx*a1r;
            float b1r = sxx*a0i + cx*a1r, b1i = -sxx*a0r + cx*a1i;
            float c0r = cy*b0r - sy*b1r, c0i = cy*b0i - sy*b1i;
            float c1r = sy*b0r + cy*b1r, c1i = sy*b0i + cy*b1i;
            sr[n]  = cz*c0r + sz*c0i;  si[n]  = cz*c0i - sz*c0r;
            sr[n1] = cz*c1r - sz*c1i;  si[n1] = cz*c1i + sz*c1r;
          }
        }
      }
    }
    #pragma unroll
    for (int n=0;n<16;n++){ MrS[n][j]=sr[n]; MiS[n][j]=si[n]; }
  }
  __syncthreads();

  // M row for this lane's amplitude k=l
  float Mr[16], Mi[16];
  #pragma unroll
  for (int j=0;j<16;j++){ Mr[j]=MrS[l][j]; Mi[j]=MiS[l][j]; }

  // ---------- per-lane weights: 4 hidden units u=4l..4l+3 ----------
  float Wg[4][4], Wi_[4][4], Wd[4][4], bg[4], bi[4], bd[4], lw4[4], lb4[4], WL[4][4];
  #pragma unroll
  for (int v=0;v<4;v++){
    const int u = 4*l+v;
    #pragma unroll
    for (int m=0;m<4;m++){
      Wg[v][m] = exw[(u      )*4+m];
      Wi_[v][m]= exw[(64 + u )*4+m];
      Wd[v][m] = exw[(128 + u)*4+m];
    }
    bg[v]=exb[u]; bi[v]=exb[64+u]; bd[v]=exb[128+u];
    lw4[v]=nrw[u]; lb4[v]=nrb[u];
  }
  float C1[4], C2[4];
  #pragma unroll
  for (int q=0;q<4;q++){
    float c1p=0.f, c2p=0.f;
    #pragma unroll
    for (int v=0;v<4;v++){
      const float whq = ew[q*192 + 128 + 4*l + v];
      WL[q][v] = whq * lw4[v];
      c1p += WL[q][v];
      c2p = fmaf(whq, lb4[v], c2p);
    }
    C1[q] = rowsum16(c1p);
    C2[q] = rowsum16(c2p);
  }

  // Z-expectation signs for amplitude k=l (qubit q <-> bit 3-q)
  const float sg0 = (l & 8) ? -1.f : 1.f;
  const float sg1 = (l & 4) ? -1.f : 1.f;
  const float sg2 = (l & 2) ? -1.f : 1.f;
  const float sg3 = (l & 1) ? -1.f : 1.f;

  const float* yxp = yx + (size_t)e * T * 4;
  float* op = out + (size_t)e * T * 64 + 4*l;

  // recurrent state
  float Sq[4] = {0.f,0.f,0.f,0.f};
  float cstv[4] = {0.f,0.f,0.f,0.f};
  float mu=0.f, rstd=0.f, w0g=0.f;
  float4 hlast = {0.f,0.f,0.f,0.f};

  // two 8-entry y batch buffers; prime with t=0..15
  float4 ya[8], yb[8];
  #pragma unroll
  for (int i=0;i<8;i++) ya[i] = *(const float4*)(yxp + (size_t)i*4);
  #pragma unroll
  for (int i=0;i<8;i++){ int tn = 8+i; if (tn > T-1) tn = T-1;
                         yb[i] = *(const float4*)(yxp + (size_t)tn*4); }

#define STEP(YV, HVOUT)                                                           \
  {                                                                               \
    const float y0 = YV.x + fmaf(w0g, C2[0], rstd*fmaf(-mu, C1[0], Sq[0]));       \
    const float y1 = YV.y + fmaf(w0g, C2[1], rstd*fmaf(-mu, C1[1], Sq[1]));       \
    const float y2 = YV.z + fmaf(w0g, C2[2], rstd*fmaf(-mu, C1[2], Sq[2]));       \
    const float y3 = YV.w + fmaf(w0g, C2[3], rstd*fmaf(-mu, C1[3], Sq[3]));       \
    float qa[4]; float qbr[4], qbi[4];                                            \
    {                                                                             \
      auto mkv = [&](float u, float& a, float& br, float& bim){                   \
        const float r2 = u*u;                                                     \
        const float c1 = frsq(fmaf(u,u,1.f));                                     \
        const float tt = (0.5f*u)*c1;                                             \
        a = fsqrt_(0.5f - tt);                                                    \
        const float bb = fsqrt_(0.5f + tt);                                       \
        const float cp = frsq(fmaf(r2,r2,1.f));                                   \
        const float sp = r2*cp;                                                   \
        br = bb*cp; bim = bb*sp;                                                  \
      };                                                                          \
      mkv(y0,qa[0],qbr[0],qbi[0]); mkv(y1,qa[1],qbr[1],qbi[1]);                   \
      mkv(y2,qa[2],qbr[2],qbi[2]); mkv(y3,qa[3],qbr[3],qbi[3]);                   \
    }                                                                             \
    float Ar[4], Ai[4], Br_[4], Bi_[4];                                           \
    Ar[0]=qa[0]*qa[1];                    Ai[0]=0.f;                              \
    Ar[1]=qa[0]*qbr[1];                   Ai[1]=qa[0]*qbi[1];                     \
    Ar[2]=qbr[0]*qa[1];                   Ai[2]=qbi[0]*qa[1];                     \
    Ar[3]=fmaf(-qbi[0],qbi[1],qbr[0]*qbr[1]); Ai[3]=fmaf(qbi[0],qbr[1],qbr[0]*qbi[1]); \
    Br_[0]=qa[2]*qa[3];                   Bi_[0]=0.f;                             \
    Br_[1]=qa[2]*qbr[3];                  Bi_[1]=qa[2]*qbi[3];                    \
    Br_[2]=qbr[2]*qa[3];                  Bi_[2]=qbi[2]*qa[3];                    \
    Br_[3]=fmaf(-qbi[2],qbi[3],qbr[2]*qbr[3]); Bi_[3]=fmaf(qbi[2],qbr[3],qbr[2]*qbi[3]); \
    float Fr=0.f, Fi=0.f;                                                         \
    _Pragma("unroll")                                                             \
    for (int m=0;m<4;m++){                                                        \
      float Gr=0.f, Gi=0.f;                                                       \
      _Pragma("unroll")                                                           \
      for (int n=0;n<4;n++){                                                      \
        const float mr=Mr[4*m+n], mi=Mi[4*m+n];                                   \
        Gr = fmaf(mr,Br_[n],Gr); Gr = fmaf(-mi,Bi_[n],Gr);                        \
        Gi = fmaf(mr,Bi_[n],Gi); Gi = fmaf( mi,Br_[n],Gi);                        \
      }                                                                           \
      Fr = fmaf(Ar[m],Gr,Fr); Fr = fmaf(-Ai[m],Gi,Fr);                            \
      Fi = fmaf(Ar[m],Gi,Fi); Fi = fmaf( Ai[m],Gr,Fi);                            \
    }                                                                             \
    const float p = fmaf(Fr,Fr, Fi*Fi);                                           \
    const float q0 = rowsum16(sg0*p);                                             \
    const float q1 = rowsum16(sg1*p);                                             \
    const float q2 = rowsum16(sg2*p);                                             \
    const float q3 = rowsum16(sg3*p);                                             \
    const float z0=y0+q0, z1=y1+q1, z2=y2+q2, z3=y3+q3;                           \
    float prearr[4];                                                              \
    _Pragma("unroll")                                                             \
    for (int v=0;v<4;v++){                                                        \
      const float og = fmaf(Wg[v][3],z3, fmaf(Wg[v][2],z2, fmaf(Wg[v][1],z1, fmaf(Wg[v][0],z0, bg[v])))); \
      const float oi = fmaf(Wi_[v][3],z3, fmaf(Wi_[v][2],z2, fmaf(Wi_[v][1],z1, fmaf(Wi_[v][0],z0, bi[v])))); \
      const float od = fmaf(Wd[v][3],z3, fmaf(Wd[v][2],z2, fmaf(Wd[v][1],z1, fmaf(Wd[v][0],z0, bd[v])))); \
      float g = sigmoidf_(og);                                                    \
      g = fminf(fmaxf(g, 0.05f), 0.95f);                                          \
      const float ig = sigmoidf_(oi);                                             \
      const float dt = tanhfast(od);                                              \
      cstv[v] = fmaf(fmaf(-0.9f, g, 0.9f), cstv[v], ig*dt);                       \
      prearr[v] = g * tanhfast(cstv[v]);                                          \
    }                                                                             \
    const float s1p = (prearr[0]+prearr[1])+(prearr[2]+prearr[3]);                \
    const float s2p = fmaf(prearr[3],prearr[3], fmaf(prearr[2],prearr[2],         \
                      fmaf(prearr[1],prearr[1], prearr[0]*prearr[0])));           \
    float t0p=0.f,t1p=0.f,t2p=0.f,t3p=0.f;                                        \
    _Pragma("unroll")                                                             \
    for (int v=0;v<4;v++){                                                        \
      t0p = fmaf(WL[0][v],prearr[v],t0p);                                         \
      t1p = fmaf(WL[1][v],prearr[v],t1p);                                         \
      t2p = fmaf(WL[2][v],prearr[v],t2p);                                         \
      t3p = fmaf(WL[3][v],prearr[v],t3p);                                         \
    }                                                                             \
    const float s1 = rowsum16(s1p);                                               \
    const float s2 = rowsum16(s2p);                                               \
    Sq[0] = rowsum16(t0p); Sq[1] = rowsum16(t1p);                                 \
    Sq[2] = rowsum16(t2p); Sq[3] = rowsum16(t3p);                                 \
    mu = s1 * (1.f/64.f);                                                         \
    const float var = fmaf(s2, 1.f/64.f, -mu*mu);                                 \
    rstd = frsq(var + 1e-5f);                                                     \
    HVOUT.x = fmaf((prearr[0]-mu)*rstd, lw4[0], lb4[0]);                          \
    HVOUT.y = fmaf((prearr[1]-mu)*rstd, lw4[1], lb4[1]);                          \
    HVOUT.z = fmaf((prearr[2]-mu)*rstd, lw4[2], lb4[2]);                          \
    HVOUT.w = fmaf((prearr[3]-mu)*rstd, lw4[3], lb4[3]);                          \
    w0g = 1.f;                                                                    \
  }

  // BATCH: 8 reg-only steps consuming YU; refill YU with TB+16 (consumed 8
  // steps later, in the batch after next); then 8 stores.
#define BATCH(TB, YU)                                                             \
  {                                                                               \
    float4 hv[8];                                                                 \
    STEP(YU[0], hv[0]);                                                           \
    STEP(YU[1], hv[1]);                                                           \
    STEP(YU[2], hv[2]);                                                           \
    STEP(YU[3], hv[3]);                                                           \
    STEP(YU[4], hv[4]);                                                           \
    STEP(YU[5], hv[5]);                                                           \
    STEP(YU[6], hv[6]);                                                           \
    STEP(YU[7], hv[7]);                                                           \
    _Pragma("unroll")                                                             \
    for (int i=0;i<8;i++){                                                        \
      int tn = (TB) + 16 + i; if (tn > T-1) tn = T-1;                             \
      YU[i] = *(const float4*)(yxp + (size_t)tn*4);                               \
    }                                                                             \
    float* obase = op + (size_t)(TB)*64;                                          \
    _Pragma("unroll")                                                             \
    for (int i=0;i<8;i++) *(float4*)(obase + (size_t)i*64) = hv[i];               \
    hlast = hv[7];                                                                \
  }

  for (int tb=0; tb<T; tb+=16){
    BATCH(tb,   ya);
    BATCH(tb+8, yb);
  }
#undef BATCH
#undef STEP

  // final hidden state h_T
  *(float4*)(out + hToff + (size_t)e*64 + 4*l) = hlast;
}

extern "C" void kernel_launch(void* const* d_in, const int* in_sizes, int n_in,
                              void* d_out, int out_size, void* d_ws, size_t ws_size,
                              hipStream_t stream)
{
  const float* x   = (const float*)d_in[0];
  const float* fw  = (const float*)d_in[1];
  const float* ew  = (const float*)d_in[2];
  const float* eb  = (const float*)d_in[3];
  const float* exw = (const float*)d_in[4];
  const float* exb = (const float*)d_in[5];
  const float* vw  = (const float*)d_in[6];
  const float* nw  = (const float*)d_in[7];
  const float* nb  = (const float*)d_in[8];

  const long long BT = in_sizes[0] / 128;           // B*T
  const int B = (int)((long long)out_size/64 - BT); // out = B*T*64 + B*64
  const int T = (int)(BT / B);

  float* yxbuf = (float*)d_ws;                      // B*T*4 floats (2 MB)

  yx_pre<<<1024, 256, 0, stream>>>(x, fw, ew, eb, yxbuf, BT);
  qssm16<<<(B+3)/4, 64, 0, stream>>>(ew, exw, exb, vw, nw, nb,
                                     yxbuf, (float*)d_out, T, B, (long long)BT*64);
}

// Round 12
// 317.268 us; speedup vs baseline: 1.4093x; 1.3918x over previous
//
#include <hip/hip_runtime.h>

#define DEV static __device__ __forceinline__

struct Cx { float r, i; };
DEV Cx cmul(Cx a, Cx b){ Cx o; o.r = a.r*b.r - a.i*b.i; o.i = a.r*b.i + a.i*b.r; return o; }

// ---- DPP helpers. quad_perm/row_ror proven R1/R4; row_shr/row_bcast are the
// canonical GCN wave64-reduce modes (gfx9 lineage, valid on CDNA). ----
template<int CTRL>
DEV float dppf(float x){
  int v = __builtin_amdgcn_update_dpp(0, __builtin_bit_cast(int, x), CTRL, 0xF, 0xF, true);
  return __builtin_bit_cast(float, v);
}
// sum over the 4 stride-4 groups within a 16-lane row (keeps lane&3 fixed) [R4-proven]
DEV float chunksum4(float v){
  v += dppf<0x124>(v);   // row_ror:4
  v += dppf<0x128>(v);   // row_ror:8
  return v;
}
DEV float rdl(float v, int l){
  return __builtin_bit_cast(float, __builtin_amdgcn_readlane(__builtin_bit_cast(int, v), l));
}
// full 64-lane sum via shr-prefix + row_bcast cascade; total lands in lane 63;
// ONE readlane broadcasts it (scalar). 6 DPP + 1 rdl (vs rowsum16+4 rdl).
DEV float red64(float v){
  v += dppf<0x111>(v);   // row_shr:1
  v += dppf<0x112>(v);   // row_shr:2
  v += dppf<0x114>(v);   // row_shr:4
  v += dppf<0x118>(v);   // row_shr:8  -> lanes 15/31/47/63 hold row sums
  v += dppf<0x142>(v);   // row_bcast:15 -> row r+1 += rowsum_r
  v += dppf<0x143>(v);   // row_bcast:31 -> rows 2,3 += (s0+s1); lane63 = total
  return rdl(v, 63);
}
// cross-row xor-sums for the throughput-parallel yx_pre kernel only
DEV float sx16(float v){ return __shfl_xor(v, 16); }
DEV float sx32(float v){ return __shfl_xor(v, 32); }
DEV float full64(float v){
  v += dppf<0xB1>(v); v += dppf<0x4E>(v); v += dppf<0x124>(v); v += dppf<0x128>(v);
  v += sx16(v); v += sx32(v);
  return v;
}

DEV float fexp(float x){ return __builtin_amdgcn_exp2f(x * 1.44269504088896341f); }
DEV float ex2(float x){ return __builtin_amdgcn_exp2f(x); }
DEV float frcp(float x){ return __builtin_amdgcn_rcpf(x); }
DEV float frsq(float x){ return __builtin_amdgcn_rsqf(x); }
DEV float fsqrt_(float x){ return __builtin_amdgcn_sqrtf(x); }

#define LOG2E 1.44269504088896341f

// =================== Kernel 1: Yx precompute (throughput-bound) [R8-proven] ===================
__global__ void yx_pre(const float* __restrict__ x, const float* __restrict__ fw,
                       const float* __restrict__ ew, const float* __restrict__ eb,
                       float* __restrict__ yx, long long nrows)
{
  const int lane = threadIdx.x & 63;
  const long long wid = (long long)blockIdx.x * (blockDim.x >> 6) + (threadIdx.x >> 6);
  const long long nw  = (long long)gridDim.x * (blockDim.x >> 6);
  float w0_,w1_,w2_,w3_,v0_,v1_,v2_,v3_;
  {
    const float f0 = fexp(fw[2*lane]), f1 = fexp(fw[2*lane+1]);
    w0_ = ew[0*192+2*lane]*f0; v0_ = ew[0*192+2*lane+1]*f1;
    w1_ = ew[1*192+2*lane]*f0; v1_ = ew[1*192+2*lane+1]*f1;
    w2_ = ew[2*192+2*lane]*f0; v2_ = ew[2*192+2*lane+1]*f1;
    w3_ = ew[3*192+2*lane]*f0; v3_ = ew[3*192+2*lane+1]*f1;
  }
  const float b0=eb[0], b1=eb[1], b2=eb[2], b3=eb[3];
  for (long long row = wid; row < nrows; row += nw){
    const float2 xv = *(const float2*)(x + row*128 + 2*lane);
    float a0 = fmaf(v0_,xv.y, w0_*xv.x);
    float a1 = fmaf(v1_,xv.y, w1_*xv.x);
    float a2 = fmaf(v2_,xv.y, w2_*xv.x);
    float a3 = fmaf(v3_,xv.y, w3_*xv.x);
    a0 = full64(a0); a1 = full64(a1); a2 = full64(a2); a3 = full64(a3);
    if (lane == 0){
      float4 o; o.x=a0+b0; o.y=a1+b1; o.z=a2+b2; o.w=a3+b3;
      *(float4*)(yx + row*4) = o;
    }
  }
}

// =================== Kernel 2: recurrence, 64 lanes per element ===================
// 1 element per wave/block. F-matvec: R4-proven row-local chunk mapping.
// Gates: 1 hidden unit per lane (R7-proven), exp2-prescaled weights.
// All 10 full-wave reductions via red64 (6 DPP + 1 rdl each).
__global__ void __launch_bounds__(64) qssm64(
  const float* __restrict__ ew, const float* __restrict__ exw,
  const float* __restrict__ exb,const float* __restrict__ vw,
  const float* __restrict__ nrw,const float* __restrict__ nrb,
  const float* __restrict__ yx, float* __restrict__ out,
  int T, long long hToff)
{
  const int lane = threadIdx.x;      // 0..63
  const int e    = blockIdx.x;       // batch element
  const int r    = lane >> 4;        // row
  const int k    = 4*r + (lane & 3); // amplitude this lane owns (F-matvec)
  const int c    = (lane >> 2) & 3;  // j-chunk this lane sums

  // ---------- build fixed circuit matrix M (16x16 complex) once [R4-verbatim] ----------
  __shared__ float MrS[16][16];
  __shared__ float MiS[16][16];
  if (lane < 16){
    const int j = lane;
    float w2[2][3][4];
    #pragma unroll
    for (int ll=0;ll<2;ll++)
      #pragma unroll
      for (int g=0;g<3;g++)
        #pragma unroll
        for (int i=0;i<4;i++) w2[ll][g][i] = 0.5f * vw[(ll*3+g)*4+i];
    float sr[16], si[16];
    #pragma unroll
    for (int n=0;n<16;n++){ sr[n] = (n==j)?1.f:0.f; si[n]=0.f; }
    #pragma unroll
    for (int ll=0;ll<2;ll++){
      #pragma unroll
      for (int cq=0;cq<4;cq++){
        const int tq=(cq+1)&3, mc=1<<(3-cq), mt=1<<(3-tq);
        #pragma unroll
        for (int n=0;n<16;n++){
          if ((n&mc) && !(n&mt)){
            const int n1 = n|mt;
            float tr=sr[n], ti=si[n];
            sr[n]=sr[n1]; si[n]=si[n1];
            sr[n1]=tr;    si[n1]=ti;
          }
        }
      }
      #pragma unroll
      for (int i=0;i<4;i++){
        const int m=1<<(3-i);
        const float cx=cosf(w2[ll][0][i]), sxx=sinf(w2[ll][0][i]);
        const float cy=cosf(w2[ll][1][i]), sy=sinf(w2[ll][1][i]);
        const float cz=cosf(w2[ll][2][i]), sz=sinf(w2[ll][2][i]);
        #pragma unroll
        for (int n=0;n<16;n++){
          if (!(n&m)){
            const int n1=n|m;
            float a0r=sr[n], a0i=si[n], a1r=sr[n1], a1i=si[n1];
            float b0r = cx*a0r + sxx*a1i, b0i = cx*a0i - sxx*a1r;
            float b1r = sxx*a0i + cx*a1r, b1i = -sxx*a0r + cx*a1i;
            float c0r = cy*b0r - sy*b1r, c0i = cy*b0i - sy*b1i;
            float c1r = sy*b0r + cy*b1r, c1i = sy*b0i + cy*b1i;
            sr[n]  = cz*c0r + sz*c0i;  si[n]  = cz*c0i - sz*c0r;
            sr[n1] = cz*c1r - sz*c1i;  si[n1] = cz*c1i + sz*c1r;
          }
        }
      }
    }
    #pragma unroll
    for (int n=0;n<16;n++){ MrS[n][j]=sr[n]; MiS[n][j]=si[n]; }
  }
  __syncthreads();

  // M fragment: row k, columns 4c..4c+3 [R4-verbatim]
  float Mr[4], Mi[4];
  #pragma unroll
  for (int m=0;m<4;m++){ Mr[m]=MrS[k][4*c+m]; Mi[m]=MiS[k][4*c+m]; }

  // ---------- per-lane weights: hidden unit u = lane [R7-proven pattern] ----------
  // exp2 pre-scaling: sigmoid(x)=rcp(1+exp2(-LOG2E*x)); tanh(x)=1-2*rcp(1+exp2(2*LOG2E*x))
  float WgP[4], WiP[4], WdP[4];
  #pragma unroll
  for (int m=0;m<4;m++){
    WgP[m] = exw[(lane      )*4+m] * (-LOG2E);
    WiP[m] = exw[(64  + lane)*4+m] * (-LOG2E);
    WdP[m] = exw[(128 + lane)*4+m] * (2.f*LOG2E);
  }
  const float bgP = exb[lane]     * (-LOG2E);
  const float biP = exb[64+lane]  * (-LOG2E);
  const float bdP = exb[128+lane] * (2.f*LOG2E);
  const float lw = nrw[lane], lb = nrb[lane];

  // entry h-columns folded through LayerNorm (R8-proven fold):
  // hdot_q = rstd*(S_q - mu*C1_q) + C2_q,  S_q = red64(Wh_q*lw*pre)
  float WL[4], C1[4], C2[4];
  #pragma unroll
  for (int q=0;q<4;q++){
    const float whq = ew[q*192 + 128 + lane];
    WL[q] = whq * lw;
    C1[q] = red64(WL[q]);
    C2[q] = red64(whq * lb);
  }

  // Z-expectation signs (0.25: p replicated x4 within row); k bits: 8->r&2, 4->r&1, 2->l&2, 1->l&1
  const float sg0 = (r & 2)    ? -0.25f : 0.25f;
  const float sg1 = (r & 1)    ? -0.25f : 0.25f;
  const float sg2 = (lane & 2) ? -0.25f : 0.25f;
  const float sg3 = (lane & 1) ? -0.25f : 0.25f;

  const float* yxp = yx + (size_t)e * T * 4;
  float* op = out + (size_t)e * T * 64 + lane;

  // recurrent state
  float S0=0.f, S1=0.f, S2=0.f, S3=0.f;
  float mu=0.f, rstd=0.f, w0g=0.f;
  float cst=0.f, h=0.f;

  float4 yA = *(const float4*)(yxp);
  float4 yB = (T>1) ? *(const float4*)(yxp + 4) : yA;

#define STEP(TCUR, YBUF)                                                          \
  {                                                                               \
    const int t_ = (TCUR);                                                        \
    /* y_q = Yx_q + hdot_q (LN-folded) */                                         \
    const float y0 = YBUF.x + fmaf(w0g, C2[0], rstd*fmaf(-mu, C1[0], S0));        \
    const float y1 = YBUF.y + fmaf(w0g, C2[1], rstd*fmaf(-mu, C1[1], S1));        \
    const float y2 = YBUF.z + fmaf(w0g, C2[2], rstd*fmaf(-mu, C1[2], S2));        \
    const float y3 = YBUF.w + fmaf(w0g, C2[3], rstd*fmaf(-mu, C1[3], S3));        \
    { const int tn = (t_+2 < T) ? (t_+2) : (T-1);                                 \
      YBUF = *(const float4*)(yxp + (size_t)tn*4); }                              \
    /* encoded qubit vectors, phase-rotated so |0> comp real [R4-verbatim] */     \
    float a0_,a1_,a2_,a3_;  Cx b0_,b1_,b2_,b3_;                                   \
    {                                                                             \
      auto mkv = [&](float u, float& a, Cx& b){                                   \
        const float r2 = u*u;                                                     \
        const float c1 = frsq(fmaf(u,u,1.f));                                     \
        const float tt = (0.5f*u)*c1;                                             \
        a = fsqrt_(fmaxf(0.5f - tt, 0.f));                                        \
        const float bb = fsqrt_(0.5f + tt);                                       \
        const float cp = frsq(fmaf(r2,r2,1.f));                                   \
        const float sp = r2*cp;                                                   \
        b.r = bb*cp; b.i = bb*sp;                                                 \
      };                                                                          \
      mkv(y0,a0_,b0_); mkv(y1,a1_,b1_); mkv(y2,a2_,b2_); mkv(y3,a3_,b3_);         \
    }                                                                             \
    /* psi0[j], j = 4c + m [R4-verbatim] */                                       \
    Cx sel0, sel1;                                                                \
    sel0.r = (lane & 8) ? b0_.r : a0_;  sel0.i = (lane & 8) ? b0_.i : 0.f;        \
    sel1.r = (lane & 4) ? b1_.r : a1_;  sel1.i = (lane & 4) ? b1_.i : 0.f;        \
    const Cx A = cmul(sel0, sel1);                                                \
    Cx B0, B1, B2, B3;                                                            \
    B0.r = a2_*a3_;            B0.i = 0.f;                                        \
    B1.r = a2_*b3_.r;          B1.i = a2_*b3_.i;                                  \
    B2.r = b2_.r*a3_;          B2.i = b2_.i*a3_;                                  \
    B3 = cmul(b2_, b3_);                                                          \
    const Cx p0 = cmul(A,B0), p1 = cmul(A,B1), p2 = cmul(A,B2), p3 = cmul(A,B3);  \
    /* F_k partial over j=4c..4c+3, in-row chunk reduction [R4-verbatim] */       \
    float t0r = fmaf(-p0.i, Mi[0], p0.r*Mr[0]);                                   \
    float t1r = fmaf(-p1.i, Mi[1], p1.r*Mr[1]);                                   \
    float t2r = fmaf(-p2.i, Mi[2], p2.r*Mr[2]);                                   \
    float t3r = fmaf(-p3.i, Mi[3], p3.r*Mr[3]);                                   \
    float t0i = fmaf( p0.i, Mr[0], p0.r*Mi[0]);                                   \
    float t1i = fmaf( p1.i, Mr[1], p1.r*Mi[1]);                                   \
    float t2i = fmaf( p2.i, Mr[2], p2.r*Mi[2]);                                   \
    float t3i = fmaf( p3.i, Mr[3], p3.r*Mi[3]);                                   \
    const float Fr = chunksum4((t0r+t1r)+(t2r+t3r));                              \
    const float Fi = chunksum4((t0i+t1i)+(t2i+t3i));                              \
    const float p = fmaf(Fr,Fr, Fi*Fi);                                           \
    /* Z expectations: 4 signed red64 (6 DPP + 1 rdl each) */                     \
    const float q0 = red64(sg0*p);                                                \
    const float q1 = red64(sg1*p);                                                \
    const float q2 = red64(sg2*p);                                                \
    const float q3 = red64(sg3*p);                                                \
    const float z0=y0+q0, z1=y1+q1, z2=y2+q2, z3=y3+q3;                           \
    /* gates for this lane's single hidden unit (exp2-prescaled weights) */       \
    const float og = fmaf(WgP[3],z3, fmaf(WgP[2],z2, fmaf(WgP[1],z1, fmaf(WgP[0],z0, bgP)))); \
    const float oi = fmaf(WiP[3],z3, fmaf(WiP[2],z2, fmaf(WiP[1],z1, fmaf(WiP[0],z0, biP)))); \
    const float od = fmaf(WdP[3],z3, fmaf(WdP[2],z2, fmaf(WdP[1],z1, fmaf(WdP[0],z0, bdP)))); \
    float g = frcp(1.f + ex2(og));                                                \
    g = fminf(fmaxf(g, 0.05f), 0.95f);                                            \
    const float ig = frcp(1.f + ex2(oi));                                         \
    const float dt = fmaf(-2.f, frcp(1.f + ex2(od)), 1.f);                        \
    cst = fmaf(fmaf(-0.9f, g, 0.9f), cst, ig*dt);                                 \
    const float th = fmaf(-2.f, frcp(1.f + ex2((2.f*LOG2E)*cst)), 1.f);           \
    const float pre = g * th;                                                     \
    /* fused LN + next-entry reductions: 6 red64 */                               \
    const float s1 = red64(pre);                                                  \
    const float s2 = red64(pre*pre);                                              \
    S0 = red64(WL[0]*pre);                                                        \
    S1 = red64(WL[1]*pre);                                                        \
    S2 = red64(WL[2]*pre);                                                        \
    S3 = red64(WL[3]*pre);                                                        \
    mu = s1 * (1.f/64.f);                                                         \
    const float var = fmaf(s2, 1.f/64.f, -mu*mu);                                 \
    rstd = frsq(var + 1e-5f);                                                     \
    h = fmaf((pre - mu)*rstd, lw, lb);                                            \
    op[(size_t)t_*64] = h;                                                        \
    w0g = 1.f;                                                                    \
  }

  for (int t=0; t<T; t+=2){
    STEP(t,   yA);
    STEP(t+1, yB);
  }
#undef STEP

  // final hidden state h_T
  out[hToff + (size_t)e*64 + lane] = h;
}

extern "C" void kernel_launch(void* const* d_in, const int* in_sizes, int n_in,
                              void* d_out, int out_size, void* d_ws, size_t ws_size,
                              hipStream_t stream)
{
  const float* x   = (const float*)d_in[0];
  const float* fw  = (const float*)d_in[1];
  const float* ew  = (const float*)d_in[2];
  const float* eb  = (const float*)d_in[3];
  const float* exw = (const float*)d_in[4];
  const float* exb = (const float*)d_in[5];
  const float* vw  = (const float*)d_in[6];
  const float* nw  = (const float*)d_in[7];
  const float* nb  = (const float*)d_in[8];

  const long long BT = in_sizes[0] / 128;           // B*T
  const int B = (int)((long long)out_size/64 - BT); // out = B*T*64 + B*64
  const int T = (int)(BT / B);

  float* yxbuf = (float*)d_ws;                      // B*T*4 floats (2 MB)

  yx_pre<<<1024, 256, 0, stream>>>(x, fw, ew, eb, yxbuf, BT);
  qssm64<<<B, 64, 0, stream>>>(ew, exw, exb, vw, nw, nb,
                               yxbuf, (float*)d_out, T, (long long)BT*64);
}